// Round 4
// baseline (140.724 us; speedup 1.0000x reference)
//
#include <hip/hip_runtime.h>
#include <cstdint>
#include <cstddef>

// ---------------- problem constants ----------------
#define NTOK 8192            // B*T = 4*2048
#define WD   4096            // n*C
#define CD   1024            // C (per-stream channels)
#define EPS_RMS 1.1920929e-07f
#define TAU_INV 10.0f        // 1/0.1

using half8  = __attribute__((ext_vector_type(8))) _Float16;
using half4v = __attribute__((ext_vector_type(4))) _Float16;
using f32x4  = __attribute__((ext_vector_type(4))) float;

// ================= Kernel P: prep = {W_branch transpose -> WT f16} + {Wcat f16} ====
__global__ __launch_bounds__(256) void k_prep(const float* __restrict__ W,
                                              _Float16* __restrict__ WT,
                                              const float* __restrict__ Wres,
                                              const float* __restrict__ Wpre,
                                              const float* __restrict__ Wpost,
                                              _Float16* __restrict__ Wcat) {
  if (blockIdx.x < 256) {
    // W_branch fp32 [k][c] -> WT f16 [c][k]
    __shared__ float tile[64][65];
    const int t  = threadIdx.x;
    const int c0 = (blockIdx.x & 15) * 64;
    const int k0 = (blockIdx.x >> 4) * 64;
    const int a = t & 63, b = t >> 6;
#pragma unroll
    for (int i = 0; i < 16; ++i) {
      int k = b + i * 4;
      tile[k][a] = W[(size_t)(k0 + k) * CD + (c0 + a)];
    }
    __syncthreads();
#pragma unroll
    for (int i = 0; i < 16; ++i) {
      int c = b + i * 4;
      WT[(size_t)(c0 + c) * CD + (k0 + a)] = (_Float16)tile[a][c];
    }
  } else {
    // concat projection weights -> Wcat f16 [32][4096], rows 24-31 zero
    const int id  = (blockIdx.x - 256) * 256 + threadIdx.x;   // 0..32767
    const int row = id >> 10;
    const int kq  = id & 1023;
    float4 v = make_float4(0.f, 0.f, 0.f, 0.f);
    if (row < 16)      v = *(const float4*)(Wres + (size_t)row * WD + kq * 4);
    else if (row < 20) v = *(const float4*)(Wpre + (size_t)(row - 16) * WD + kq * 4);
    else if (row < 24) v = *(const float4*)(Wpost + (size_t)(row - 20) * WD + kq * 4);
    half4v h;
    h[0] = (_Float16)v.x; h[1] = (_Float16)v.y; h[2] = (_Float16)v.z; h[3] = (_Float16)v.w;
    *(half4v*)(Wcat + (size_t)row * WD + kq * 4) = h;
  }
}

// ================= Kernel B: MFMA stats v4 — barrier-free K-loop =================
// 512 thr (8 waves), 16 tokens/block. Wave p owns K-chunk [p*512, p*512+512).
// A-fragments loaded DIRECTLY from global x (lane l: row l&15, k=(l>>4)*8..+8),
// B-fragments directly from L2-hot Wcat. No LDS, no barriers in the K-loop.
// One barrier merges partials; tail: sinkhorn (waves 0-3) || x_pre (waves 4-7).
#define KCH 512
__global__ __launch_bounds__(512, 6) void k_stats4(
    const float* __restrict__ x, const _Float16* __restrict__ Wcat,
    const float* __restrict__ baseRes, const float* __restrict__ basePre,
    const float* __restrict__ basePost, const float* __restrict__ gate,
    float* __restrict__ HpostOut, float* __restrict__ HresF,
    _Float16* __restrict__ xpre)
{
  __shared__ float Lpart[8][16][32];   // 16.4 KB
  __shared__ float ssPart[8][16];
  __shared__ float invS[16];
  __shared__ float HpreS[16][4];

  const int t    = threadIdx.x;          // 0..511
  const int lane = t & 63;
  const int p    = t >> 6;               // wave id = K-chunk
  const int tok0 = blockIdx.x * 16;
  const int fr   = lane & 15, kg = lane >> 4;

  const float*    xr = x    + (size_t)(tok0 + fr) * WD + p * KCH + kg * 8;
  const _Float16* w0 = Wcat + (size_t)fr * WD        + p * KCH + kg * 8;
  const _Float16* w1 = Wcat + (size_t)(16 + fr) * WD + p * KCH + kg * 8;

  f32x4 acc0 = {0.f, 0.f, 0.f, 0.f};
  f32x4 acc1 = {0.f, 0.f, 0.f, 0.f};
  float ss = 0.f;

  // ---- barrier-free K-loop: 16 steps of 32 channels, fully unrolled ----
#pragma unroll
  for (int kt = 0; kt < 16; ++kt) {
    const int ko = kt * 32;
    const float4 u = *(const float4*)(xr + ko);
    const float4 v = *(const float4*)(xr + ko + 4);
    const half8 b0 = *(const half8*)(w0 + ko);
    const half8 b1 = *(const half8*)(w1 + ko);
    ss += u.x * u.x + u.y * u.y + u.z * u.z + u.w * u.w;
    ss += v.x * v.x + v.y * v.y + v.z * v.z + v.w * v.w;
    half8 a;
    a[0] = (_Float16)u.x; a[1] = (_Float16)u.y; a[2] = (_Float16)u.z; a[3] = (_Float16)u.w;
    a[4] = (_Float16)v.x; a[5] = (_Float16)v.y; a[6] = (_Float16)v.z; a[7] = (_Float16)v.w;
    acc0 = __builtin_amdgcn_mfma_f32_16x16x32_f16(a, b0, acc0, 0, 0, 0);
    acc1 = __builtin_amdgcn_mfma_f32_16x16x32_f16(a, b1, acc1, 0, 0, 0);
  }

  // ---- sumsq: reduce across kg groups (lanes sharing l&15) ----
  ss += __shfl_xor(ss, 16);
  ss += __shfl_xor(ss, 32);
  if (lane < 16) ssPart[p][lane] = ss;

  // ---- partial logits scatter (C/D map: row=kg*4+r, col=fr) ----
#pragma unroll
  for (int r = 0; r < 4; ++r) {
    Lpart[p][kg * 4 + r][fr]      = acc0[r];
    Lpart[p][kg * 4 + r][16 + fr] = acc1[r];
  }
  __syncthreads();

  // ---- per-token finalize ----
  if (t < 16) {
    float s = 0.f;
#pragma unroll
    for (int pp = 0; pp < 8; ++pp) s += ssPart[pp][t];
    const float inv = rsqrtf(s * (1.0f / (float)WD) + EPS_RMS);
    invS[t] = inv;
    float pr[4], q[4];
#pragma unroll
    for (int j = 0; j < 4; ++j) {
      float lp = 0.f, lq = 0.f;
#pragma unroll
      for (int pp = 0; pp < 8; ++pp) {
        lp += Lpart[pp][t][16 + j];
        lq += Lpart[pp][t][20 + j];
      }
      pr[j] = fmaf(lp, inv, basePre[j]);
      q[j]  = fmaf(lq, inv, basePost[j]);
    }
    {
      const float m = fmaxf(fmaxf(pr[0], pr[1]), fmaxf(pr[2], pr[3]));
      float s2 = 0.f;
#pragma unroll
      for (int j = 0; j < 4; ++j) { pr[j] = __expf(pr[j] - m); s2 += pr[j]; }
      const float rs = 1.0f / s2;
#pragma unroll
      for (int j = 0; j < 4; ++j) HpreS[t][j] = pr[j] * rs;
    }
    {
      const float m = fmaxf(fmaxf(q[0], q[1]), fmaxf(q[2], q[3]));
      float s2 = 0.f;
#pragma unroll
      for (int j = 0; j < 4; ++j) { q[j] = __expf(q[j] - m); s2 += q[j]; }
      const float rs = 1.0f / s2;
      float4 qv; qv.x = q[0] * rs; qv.y = q[1] * rs; qv.z = q[2] * rs; qv.w = q[3] * rs;
      *(float4*)(HpostOut + (size_t)(tok0 + t) * 4) = qv;
    }
  }
  __syncthreads();

  if (t < 256) {
    // ---- inlined Sinkhorn: waves 0-3, 16 lanes per token ----
    const int tk  = t >> 4;
    const int l16 = t & 15;
    float Lsum = 0.f;
#pragma unroll
    for (int pp = 0; pp < 8; ++pp) Lsum += Lpart[pp][tk][l16];
    const float Z = fmaf(Lsum, invS[tk], baseRes[l16]) * TAU_INV;
    const int i = l16 >> 2, j = l16 & 3;
    float u = 0.0f, v = 0.0f;
    for (int itr = 0; itr < 50; ++itr) {
      float a = Z + v;
      float m = fmaxf(a, __shfl_xor(a, 1)); m = fmaxf(m, __shfl_xor(m, 2));
      float s = __expf(a - m);
      s += __shfl_xor(s, 1); s += __shfl_xor(s, 2);
      u = -(m + __logf(s));
      float b = Z + u;
      float m2 = fmaxf(b, __shfl_xor(b, 4)); m2 = fmaxf(m2, __shfl_xor(m2, 8));
      float s2 = __expf(b - m2);
      s2 += __shfl_xor(s2, 4); s2 += __shfl_xor(s2, 8);
      v = -(m2 + __logf(s2));
    }
    const float H = __expf(Z + u + v);
    const float gg = 1.0f / (1.0f + __expf(-gate[0]));
    HresF[(size_t)(tok0 + tk) * 16 + l16] = gg * H + ((i == j) ? (1.0f - gg) : 0.0f);
  } else {
    // ---- phase 2: waves 4-7, one 16-lane quarter per token (x is L2/L3-hot) ----
    const int q16 = (t - 256) >> 4;
    const int l16 = t & 15;
    const int tok = tok0 + q16;
    const float p0 = HpreS[q16][0], p1 = HpreS[q16][1];
    const float p2 = HpreS[q16][2], p3 = HpreS[q16][3];
    const float* xrow = x + (size_t)tok * WD;
    _Float16* xp = xpre + (size_t)tok * CD;
#pragma unroll 2
    for (int it = 0; it < 16; ++it) {
      const int c4 = it * 64 + l16 * 4;
      const float4 s0 = *(const float4*)(xrow + c4);
      const float4 s1 = *(const float4*)(xrow + CD + c4);
      const float4 s2 = *(const float4*)(xrow + 2 * CD + c4);
      const float4 s3 = *(const float4*)(xrow + 3 * CD + c4);
      half4v h;
      h[0] = (_Float16)(p0 * s0.x + p1 * s1.x + p2 * s2.x + p3 * s3.x);
      h[1] = (_Float16)(p0 * s0.y + p1 * s1.y + p2 * s2.y + p3 * s3.y);
      h[2] = (_Float16)(p0 * s0.z + p1 * s1.z + p2 * s2.z + p3 * s3.z);
      h[3] = (_Float16)(p0 * s0.w + p1 * s1.w + p2 * s2.w + p3 * s3.w);
      *(half4v*)(xp + c4) = h;
    }
  }
}

// ================= Kernel D: y = x_pre @ W_branch (f16 MFMA) + fused epilogue =====
#define LDK 72
__global__ __launch_bounds__(256, 2) void k_gemm_epi(
    const _Float16* __restrict__ xpre, const _Float16* __restrict__ WT,
    const float* __restrict__ x, const float* __restrict__ HresF,
    const float* __restrict__ Hpost, float* __restrict__ out)
{
  __shared__ _Float16 As[128 * LDK];
  __shared__ _Float16 Bs[128 * LDK];
  const int tid  = threadIdx.x;
  const int nb   = blockIdx.x & 7;
  const int mb   = blockIdx.x >> 3;
  const int tok0 = mb * 128;
  const int cb   = nb * 128;
  const int lane = tid & 63, wid = tid >> 6;
  const int wr = (wid >> 1) * 64, wc = (wid & 1) * 64;
  const int fr = lane & 15, kg = lane >> 4;

  f32x4 acc[4][4];
#pragma unroll
  for (int m = 0; m < 4; ++m)
#pragma unroll
    for (int n = 0; n < 4; ++n) { f32x4 z = {0.f, 0.f, 0.f, 0.f}; acc[m][n] = z; }

  for (int kt = 0; kt < 16; ++kt) {
#pragma unroll
    for (int i = 0; i < 4; ++i) {
      const int chunk = tid + i * 256;
      const int r = chunk >> 3;
      const int ko = (chunk & 7) * 8;
      *(half8*)&As[r * LDK + ko] =
          *(const half8*)&xpre[(size_t)(tok0 + r) * CD + kt * 64 + ko];
      *(half8*)&Bs[r * LDK + ko] =
          *(const half8*)&WT[(size_t)(cb + r) * CD + kt * 64 + ko];
    }
    __syncthreads();
#pragma unroll
    for (int kk = 0; kk < 2; ++kk) {
      half8 a[4], b[4];
#pragma unroll
      for (int m = 0; m < 4; ++m)
        a[m] = *(const half8*)&As[(wr + m * 16 + fr) * LDK + kk * 32 + kg * 8];
#pragma unroll
      for (int n = 0; n < 4; ++n)
        b[n] = *(const half8*)&Bs[(wc + n * 16 + fr) * LDK + kk * 32 + kg * 8];
#pragma unroll
      for (int m = 0; m < 4; ++m)
#pragma unroll
        for (int n = 0; n < 4; ++n)
          acc[m][n] = __builtin_amdgcn_mfma_f32_16x16x32_f16(a[m], b[n], acc[m][n], 0, 0, 0);
    }
    __syncthreads();
  }

  float* Hs = (float*)As;
  for (int idx = tid; idx < 128 * 20; idx += 256) {
    const int tl = idx / 20, e = idx % 20;
    Hs[idx] = (e < 16) ? HresF[(size_t)(tok0 + tl) * 16 + e]
                       : Hpost[(size_t)(tok0 + tl) * 4 + (e - 16)];
  }
  __syncthreads();

#pragma unroll
  for (int m = 0; m < 4; ++m) {
#pragma unroll
    for (int reg = 0; reg < 4; ++reg) {
      const int tl = wr + m * 16 + (lane >> 4) * 4 + reg;
      const size_t trow = (size_t)(tok0 + tl) * WD;
      float H[20];
#pragma unroll
      for (int e = 0; e < 20; ++e) H[e] = Hs[tl * 20 + e];
#pragma unroll
      for (int n = 0; n < 4; ++n) {
        const int c = cb + wc + n * 16 + (lane & 15);
        const float yv = acc[m][n][reg];
        const float x0 = x[trow + c];
        const float x1 = x[trow + CD + c];
        const float x2 = x[trow + 2 * CD + c];
        const float x3 = x[trow + 3 * CD + c];
#pragma unroll
        for (int i = 0; i < 4; ++i) {
          out[trow + i * CD + c] =
              H[i * 4 + 0] * x0 + H[i * 4 + 1] * x1 + H[i * 4 + 2] * x2 +
              H[i * 4 + 3] * x3 + H[16 + i] * yv;
        }
      }
    }
  }
}

// ================= launcher =================
extern "C" void kernel_launch(void* const* d_in, const int* in_sizes, int n_in,
                              void* d_out, int out_size, void* d_ws, size_t ws_size,
                              hipStream_t stream) {
  const float* x        = (const float*)d_in[0];
  const float* Wres     = (const float*)d_in[1];
  const float* Wpre     = (const float*)d_in[2];
  const float* Wpost    = (const float*)d_in[3];
  const float* baseRes  = (const float*)d_in[4];
  const float* basePre  = (const float*)d_in[5];
  const float* basePost = (const float*)d_in[6];
  const float* gate     = (const float*)d_in[7];
  const float* Wb       = (const float*)d_in[8];
  float* out = (float*)d_out;

  char* ws = (char*)d_ws;
  _Float16* xpre  = (_Float16*)(ws);                       // 16,777,216 B
  _Float16* WT    = (_Float16*)(ws + 16777216);            //  2,097,152 B
  float*    HresF = (float*)(ws + 19398656);               //    524,288 B
  float*    Hpst  = (float*)(ws + 19922944);               //    131,072 B
  _Float16* Wcat  = (_Float16*)(ws + 20054016);            //    262,144 B

  k_prep<<<384, 256, 0, stream>>>(Wb, WT, Wres, Wpre, Wpost, Wcat);
  k_stats4<<<512, 512, 0, stream>>>(x, Wcat, baseRes, basePre, basePost, gate,
                                    Hpst, HresF, xpre);
  k_gemm_epi<<<512, 256, 0, stream>>>(xpre, WT, x, HresF, Hpst, out);
}